// Round 17
// baseline (59.763 us; speedup 1.0000x reference)
//
#include <hip/hip_runtime.h>
#include <hip/hip_fp16.h>

#define NB 4
#define CI 64
#define CO 128
#define HH 128
#define WW 128
#define HWSZ (HH*WW)
#define TOTPX (NB*HWSZ)     // 65536
#define NN 9

using half8 = __attribute__((ext_vector_type(8))) _Float16;
using f32x4 = __attribute__((ext_vector_type(4))) float;
using f32x2 = __attribute__((ext_vector_type(2))) float;

// ---- K0: prep W (fragment-major f16) + offset-conv weights (tap-major) ----
__global__ __launch_bounds__(256) void k_prep_w(const float* __restrict__ w,
                                                unsigned short* __restrict__ waF,
                                                const float* __restrict__ w_off,
                                                float* __restrict__ wP) {
    int t = blockIdx.x * 256 + threadIdx.x;
    if (t < CO * 576) {
        int oc = t / 576, r = t - oc * 576;
        int c = r / 9, n = r - c * 9;
        int i = oc >> 4, col = oc & 15;
        int ks = c >> 5, koct = (c >> 3) & 3, e = c & 7;
        int lane = koct * 16 + col;
        waF[(n * 16 + i * 2 + ks) * 512 + lane * 8 + e] =
            __half_as_ushort(__float2half_rn(w[t]));
    }
    if (t < 18 * 576) {
        int oc = t / 576, r = t - oc * 576;
        wP[r * 20 + oc] = w_off[t];
    }
}

// ---- K0b: x NCHW fp32 -> xT NHWC f16 (LDS transpose; r3-proven) ----
__global__ __launch_bounds__(256) void k_nhwc(const float* __restrict__ x,
                                              unsigned short* __restrict__ xT) {
    __shared__ float tl[64 * 65];
    int bid = blockIdx.x;
    int b = bid >> 8, rem = bid & 255, y = rem >> 1, x0 = (rem & 1) << 6;
    int t = threadIdx.x;
    #pragma unroll
    for (int i = 0; i < 16; i++) {
        int idx = t + i * 256;
        int c = idx >> 6, xl = idx & 63;
        tl[c * 65 + xl] = x[((size_t)(b * CI + c) * HH + y) * WW + x0 + xl];
    }
    __syncthreads();
    #pragma unroll
    for (int i = 0; i < 16; i++) {
        int idx = t + i * 256;
        int xl = idx >> 6, c = idx & 63;
        xT[(size_t)((b * HH + y) * WW + x0 + xl) * 64 + c] =
            __half_as_ushort(__float2half_rn(tl[c * 65 + xl]));
    }
}

// ---- K1 (fused): offset conv -> LDS descriptors -> gather + MFMA ----
// Block = 1 row (128 px x 128 oc), 512 thr, grid 512 (8 XCD x 64).
// ph1: 128 px x 4 ch-groups(16) [r8 numerics]; ph2: 8 waves x 16 px [r13 ITER].
__global__ __launch_bounds__(512, 4) void k_fused(
    const float* __restrict__ x, const unsigned short* __restrict__ xT,
    const unsigned short* __restrict__ waF, const float* __restrict__ wP,
    const float* __restrict__ b_off, float* __restrict__ out)
{
    __shared__ __align__(16) char LB[62976];
    f32x2*          sm  = (f32x2*)LB;                        // ph1: 36864 B
    unsigned short* WlA = (unsigned short*)LB;               // ph2: 16 KB
    unsigned short* WlB = (unsigned short*)(LB + 16384);     // ph2: 16 KB
    unsigned short* Rd  = (unsigned short*)(LB + 32768);     // ph2: 16 KB
    uchar4*         dCl = (uchar4*)(LB + 49152);             // 4608 B
    ushort4*        dGl = (ushort4*)(LB + 49152 + 4608);     // 9216 B

    int bid0 = blockIdx.x;                     // 512 = 8 XCD x 64 chunked
    int bid  = ((bid0 & 7) << 6) | (bid0 >> 3);
    int b = bid >> 7, y = bid & 127;
    int t = threadIdx.x;

    // ================= phase 1: offset conv (r8 numerics) =================
    {
        int px = t & 127;
        int g  = __builtin_amdgcn_readfirstlane(t >> 7);   // 4 groups x 16 ch
        f32x2 a2[9];
        #pragma unroll
        for (int i = 0; i < 9; i++) a2[i] = {0.f, 0.f};

        #pragma unroll 2
        for (int ci = 0; ci < 16; ci++) {
            int cg = g * 16 + ci;
            const float* xpl = x + (size_t)(b * CI + cg) * HWSZ;
            #pragma unroll
            for (int ky = 0; ky < 3; ky++) {
                int yy = y + ky - 1;
                if ((unsigned)yy >= 128u) continue;         // uniform skip
                const float* xr = xpl + yy * WW;
                #pragma unroll
                for (int kx = 0; kx < 3; kx++) {
                    int xx = px + kx - 1;
                    float v = ((unsigned)xx < 128u) ? xr[xx] : 0.f;
                    const f32x2* wr2 = (const f32x2*)(wP + (cg * 9 + ky * 3 + kx) * 20);
                    f32x2 v2 = {v, v};
                    #pragma unroll
                    for (int j = 0; j < 9; j++)
                        a2[j] = __builtin_elementwise_fma(v2, wr2[j], a2[j]);
                }
            }
        }
        #pragma unroll
        for (int i = 0; i < 9; i++) sm[t * 9 + i] = a2[i];
    }
    __syncthreads();

    // ---- reduce (4 groups ascending) + descriptors into LDS ----
    for (int task = t; task < 1152; task += 512) {
        int p2 = task & 127, n = task >> 7;
        float ay = b_off[n], ax = b_off[9 + n];
        int jy = n >> 1, cy = n & 1;
        int jx = (9 + n) >> 1, cx = (9 + n) & 1;
        #pragma unroll
        for (int gg = 0; gg < 4; gg++) {
            ay += sm[(gg * 128 + p2) * 9 + jy][cy];
            ax += sm[(gg * 128 + p2) * 9 + jx][cx];
        }
        float py  = (float)(y + (n / 3)) + ay;
        float pxc = (float)(p2 + (n % 3)) + ax;
        float fy = floorf(py), fx = floorf(pxc);
        if (py  < 1.f || py  > 128.f) py  = fy;       // pad snap
        if (pxc < 1.f || pxc > 128.f) pxc = fx;
        py  = fminf(fmaxf(py,  0.f), 129.f);
        pxc = fminf(fmaxf(pxc, 0.f), 129.f);

        fy = floorf(py); fx = floorf(pxc);
        int y0 = (int)fy, x0i = (int)fx;              // padded coords [0,129]
        int y1 = min(y0 + 1, 129), x1 = min(x0i + 1, 129);
        float wyl = 1.f + (fy - py);
        float wyr = 1.f - ((float)y1 - py);
        float wxl = 1.f + (fx - pxc);
        float wxr = 1.f - ((float)x1 - pxc);
        float glt = wyl * wxl, grb = wyr * wxr, glb = wyl * wxr, grt = wyr * wxl;
        if ((unsigned)(y0  - 1) >= 128u) { glt = 0.f; glb = 0.f; }
        if ((unsigned)(y1  - 1) >= 128u) { grb = 0.f; grt = 0.f; }
        if ((unsigned)(x0i - 1) >= 128u) { glt = 0.f; grt = 0.f; }
        if ((unsigned)(x1  - 1) >= 128u) { grb = 0.f; glb = 0.f; }

        uchar4 cu;
        cu.x = (unsigned char)min(max(y0  - 1, 0), 127);
        cu.y = (unsigned char)min(max(y1  - 1, 0), 127);
        cu.z = (unsigned char)min(max(x0i - 1, 0), 127);
        cu.w = (unsigned char)min(max(x1  - 1, 0), 127);
        ushort4 gu;
        gu.x = __half_as_ushort(__float2half_rn(glt));
        gu.y = __half_as_ushort(__float2half_rn(grb));
        gu.z = __half_as_ushort(__float2half_rn(glb));
        gu.w = __half_as_ushort(__float2half_rn(grt));
        dCl[n * 128 + p2] = cu;
        dGl[n * 128 + p2] = gu;
    }
    __syncthreads();    // sm dead; Wl/Rd region live from here

    // ================= phase 2: gather + MFMA (r13 structure) =================
    int lane = t & 63, wv = t >> 6;
    int col = lane & 15, koct = lane >> 4;     // MFMA role
    int gp = lane >> 2, gq = lane & 3;         // gather role
    int qo = gq * 8;
    int pxG = wv * 16 + gp;                    // pixel within row
    const unsigned short* xb = xT + (size_t)b * (HWSZ * 64);
    unsigned short* Rdw = Rd + wv * 1024;

    half8 raw[8];
    f32x4 acc[8];
    #pragma unroll
    for (int i = 0; i < 8; i++) acc[i] = {0.f, 0.f, 0.f, 0.f};

    auto stage = [&](int kc, unsigned short* buf) {
        #pragma unroll
        for (int p = 0; p < 2; p++) {
            const unsigned short* gsrc = waF + kc * 8192 + wv * 1024 + p * 512 + lane * 8;
            __builtin_amdgcn_global_load_lds(
                (const __attribute__((address_space(1))) unsigned int*)gsrc,
                (__attribute__((address_space(3))) unsigned int*)(buf + wv * 1024 + p * 512),
                16, 0, 0);
        }
    };
    auto issue = [&](uchar4 cu) {              // quad-coalesced gather
        int o00 = (((int)cu.x * WW) + (int)cu.z) << 6;
        int o11 = (((int)cu.y * WW) + (int)cu.w) << 6;
        int o01 = (((int)cu.x * WW) + (int)cu.w) << 6;
        int o10 = (((int)cu.y * WW) + (int)cu.z) << 6;
        raw[0] = *(const half8*)(xb + o00 + qo);
        raw[1] = *(const half8*)(xb + o11 + qo);
        raw[2] = *(const half8*)(xb + o01 + qo);
        raw[3] = *(const half8*)(xb + o10 + qo);
        raw[4] = *(const half8*)(xb + o00 + qo + 32);
        raw[5] = *(const half8*)(xb + o11 + qo + 32);
        raw[6] = *(const half8*)(xb + o01 + qo + 32);
        raw[7] = *(const half8*)(xb + o10 + qo + 32);
    };
    auto combine_store = [&](ushort4 gu) {
        __half2 q0 = __half2half2(__ushort_as_half(gu.x));
        __half2 q1 = __half2half2(__ushort_as_half(gu.y));
        __half2 q2 = __half2half2(__ushort_as_half(gu.z));
        __half2 q3 = __half2half2(__ushort_as_half(gu.w));
        #pragma unroll
        for (int ks = 0; ks < 2; ks++) {
            __half2 vm[4];
            #pragma unroll
            for (int m = 0; m < 4; m++) {
                __half2 v = __hmul2(((const __half2*)&raw[ks * 4 + 0])[m], q0);
                v = __hfma2(((const __half2*)&raw[ks * 4 + 1])[m], q1, v);
                v = __hfma2(((const __half2*)&raw[ks * 4 + 2])[m], q2, v);
                v = __hfma2(((const __half2*)&raw[ks * 4 + 3])[m], q3, v);
                vm[m] = v;
            }
            int gz = (4 * ks + gq) ^ (gp & 7);
            *(uint4*)(Rdw + gp * 64 + gz * 8) = *(const uint4*)vm;
        }
    };

    // ---- prologue ----
    stage(0, WlA);
    __builtin_amdgcn_sched_barrier(0);
    uchar4  cuA = dCl[pxG];        ushort4 guA = dGl[pxG];
    uchar4  cuB = dCl[128 + pxG];  ushort4 guB = dGl[128 + pxG];
    __builtin_amdgcn_sched_barrier(0);
    issue(cuA);
    __builtin_amdgcn_sched_barrier(0);
    asm volatile("s_waitcnt vmcnt(8)" ::: "memory");   // W(0) done; gathers fly
    __builtin_amdgcn_s_barrier();
    __builtin_amdgcn_sched_barrier(0);

#define ITER(KC)                                                              \
  {                                                                           \
    if ((KC) < 8) stage((KC) + 1, ((KC) & 1) ? WlA : WlB);                    \
    __builtin_amdgcn_sched_barrier(0);                                        \
    uchar4 cuN; ushort4 guN;                                                  \
    if ((KC) < 7) { cuN = dCl[((KC)+2) * 128 + pxG];                          \
                    guN = dGl[((KC)+2) * 128 + pxG]; }                        \
    __builtin_amdgcn_sched_barrier(0);                                        \
    combine_store(guA);                                                       \
    asm volatile("s_waitcnt lgkmcnt(0)" ::: "memory");                        \
    __builtin_amdgcn_sched_barrier(0);                                        \
    half8 bfr[2];                                                             \
    _Pragma("unroll")                                                         \
    for (int ks = 0; ks < 2; ks++) {                                          \
      int gz = (4 * ks + koct) ^ (col & 7);                                   \
      bfr[ks] = *(const half8*)(Rdw + col * 64 + gz * 8);                     \
    }                                                                         \
    __builtin_amdgcn_sched_barrier(0);                                        \
    if ((KC) < 8) issue(cuB);                                                 \
    __builtin_amdgcn_sched_barrier(0);                                        \
    __builtin_amdgcn_s_setprio(1);                                            \
    { const unsigned short* wl = ((KC) & 1) ? WlB : WlA;                      \
      _Pragma("unroll")                                                       \
      for (int ks = 0; ks < 2; ks++)                                          \
        _Pragma("unroll")                                                     \
        for (int i = 0; i < 8; i++) {                                         \
          half8 af = *(const half8*)(wl + (i * 2 + ks) * 512 + lane * 8);     \
          acc[i] = __builtin_amdgcn_mfma_f32_16x16x32_f16(af, bfr[ks],        \
                                                          acc[i], 0, 0, 0); } } \
    __builtin_amdgcn_s_setprio(0);                                            \
    if ((KC) < 8) {                                                           \
      asm volatile("s_waitcnt vmcnt(8)" ::: "memory");                        \
      __builtin_amdgcn_s_barrier();                                           \
      __builtin_amdgcn_sched_barrier(0);                                      \
    }                                                                         \
    cuA = cuB; guA = guB;                                                     \
    cuB = ((KC) < 7) ? cuN : cuB; guB = ((KC) < 7) ? guN : guB;               \
  }

    ITER(0) ITER(1) ITER(2) ITER(3) ITER(4) ITER(5) ITER(6) ITER(7) ITER(8)
#undef ITER

    // epilogue: D row -> oc, col -> px
    int ob0 = b * CO * HWSZ + y * WW + wv * 16 + col;
    #pragma unroll
    for (int i = 0; i < 8; i++)
        #pragma unroll
        for (int r = 0; r < 4; r++) {
            int oc = i * 16 + koct * 4 + r;
            out[ob0 + oc * HWSZ] = acc[i][r];
        }
}

extern "C" void kernel_launch(void* const* d_in, const int* in_sizes, int n_in,
                              void* d_out, int out_size, void* d_ws, size_t ws_size,
                              hipStream_t stream) {
    const float* x      = (const float*)d_in[0];
    const float* w_off  = (const float*)d_in[1];
    const float* b_off  = (const float*)d_in[2];
    const float* w_conv = (const float*)d_in[3];
    float* out = (float*)d_out;

    // ws: xT 8MB | waF 144KB | wP 46KB
    char* wsb = (char*)d_ws;
    unsigned short* xT  = (unsigned short*)wsb;
    unsigned short* waF = (unsigned short*)(wsb + (size_t)TOTPX * 64 * 2);
    float*          wP  = (float*)(wsb + (size_t)TOTPX * 64 * 2 + (size_t)CO * 576 * 2);

    k_prep_w<<<(CO * 576 + 255) / 256, 256, 0, stream>>>(w_conv, waF, w_off, wP);
    k_nhwc<<<1024, 256, 0, stream>>>(x, xT);
    k_fused<<<512, 512, 0, stream>>>(x, xT, waF, wP, b_off, out);
}